// Round 11
// baseline (242.368 us; speedup 1.0000x reference)
//
#include <hip/hip_runtime.h>
#include <hip/hip_cooperative_groups.h>

namespace cg = cooperative_groups;

#define S_   2048
#define D_   1024
#define H_   16
#define HD_  64
#define NTOK 8192   // B*S
#define QKS  2048   // row stride of fused QK output
#define QSCALE 0.18033688f  // 0.125 * log2(e) — folded into Q at projection time

typedef __attribute__((ext_vector_type(8))) __bf16 bf16x8;
typedef __attribute__((ext_vector_type(4))) __bf16 bf16x4;
typedef __attribute__((ext_vector_type(4))) float  f32x4;
typedef __attribute__((ext_vector_type(4))) short  short4v;

#define GPTR(p) ((__attribute__((address_space(1))) void*)(unsigned long long)(p))
#define LPTR(p) ((__attribute__((address_space(3))) void*)(p))

// ---------------- prep unit: u<4096 cast x->bf16, else transpose weights ----------------
__device__ __forceinline__ void prep_unit(int u, const float* __restrict__ x,
                                          __bf16* __restrict__ xb,
                                          const float* __restrict__ Wq,
                                          const float* __restrict__ Wk,
                                          const float* __restrict__ Wv,
                                          const float* __restrict__ Wo,
                                          __bf16* __restrict__ wqkt,
                                          __bf16* __restrict__ wvt,
                                          __bf16* __restrict__ wot,
                                          float* __restrict__ ts) {   // [32][33] scratch
    if (u < 4096) {
        int i = u * 2048 + threadIdx.x * 8;
        f32x4 a = *(const f32x4*)(x + i);
        f32x4 b = *(const f32x4*)(x + i + 4);
        bf16x8 o;
#pragma unroll
        for (int j = 0; j < 4; j++) { o[j] = (__bf16)a[j]; o[4 + j] = (__bf16)b[j]; }
        *(bf16x8*)(xb + i) = o;
        return;
    }
    float (*t)[33] = (float(*)[33])ts;
    const int tt = u - 4096;
    const int widx = tt >> 10, r = tt & 1023;
    const float* W;
    __bf16* Wt;
    switch (widx) {
        case 0: W = Wq; Wt = wqkt; break;
        case 1: W = Wk; Wt = wqkt + (size_t)D_ * D_; break;
        case 2: W = Wv; Wt = wvt; break;
        default: W = Wo; Wt = wot; break;
    }
    const int i0 = (r & 31) * 32, j0 = (r >> 5) * 32;
    const int tx = threadIdx.x & 31, ty = threadIdx.x >> 5;
#pragma unroll
    for (int rr = 0; rr < 32; rr += 8)
        t[ty + rr][tx] = W[(size_t)(i0 + ty + rr) * D_ + j0 + tx];
    __syncthreads();
#pragma unroll
    for (int rr = 0; rr < 32; rr += 8)
        Wt[(size_t)(j0 + ty + rr) * D_ + i0 + tx] = (__bf16)t[tx][ty + rr];
    __syncthreads();   // scratch reused by next unit / As by qkv phase
}

// ---------------- shared GEMM body (bf16 out, optional scale) ----------------
// Measured optimum of this family (qkv 763 TF, FETCH 41MB, 0 conflicts).
// Full deviation sweep regressed: dbuf(R10), 8-phase 256^2(R11), 1-barrier
// 256x128(R12), setprio(R13), BK=64(R15). 128x128, BK=32, bar;stage;bar;
// compute with 2-3 blocks/CU TLP covering the drain (m114 mechanism).
// vperm=1: swap 8B halves of 16B output chunks for rows with bit3 set;
// consumed by k_attn's V-read (verified R7: attn bank conflicts 4.3M -> 0).
__device__ __forceinline__ void gemm_body_bf16(const __bf16* __restrict__ A,
                                               const __bf16* __restrict__ Bt,
                                               __bf16* __restrict__ C,
                                               int N, int K, int tm, int tn,
                                               float scale, int vperm,
                                               __bf16* As, __bf16* Bs) {
    const int tid  = threadIdx.x;
    const int wave = tid >> 6, lane = tid & 63;
    const int quad = lane >> 4, l16 = lane & 15;
    const int wm = (wave & 1) * 64, wn = (wave >> 1) * 64;
    f32x4 acc[4][4] = {};

    for (int k0 = 0; k0 < K; k0 += 32) {
        __syncthreads();
#pragma unroll
        for (int s = 0; s < 2; s++) {
            const int cb = s * 256 + wave * 64;
            const int c  = cb + lane;
            const int row = c >> 2;
            const int kc  = ((c & 3) ^ ((row >> 1) & 3)) * 8;  // swizzled k-chunk
            __builtin_amdgcn_global_load_lds(GPTR(A + (size_t)(tm + row) * K + k0 + kc),
                                             LPTR(As + cb * 8), 16, 0, 0);
            __builtin_amdgcn_global_load_lds(GPTR(Bt + (size_t)(tn + row) * K + k0 + kc),
                                             LPTR(Bs + cb * 8), 16, 0, 0);
        }
        __syncthreads();

        bf16x8 af[4], bf[4];
#pragma unroll
        for (int mi = 0; mi < 4; mi++) {
            const int rf = wm + mi * 16 + l16;
            af[mi] = *(const bf16x8*)&As[rf * 32 + (quad ^ ((rf >> 1) & 3)) * 8];
        }
#pragma unroll
        for (int ni = 0; ni < 4; ni++) {
            const int rf = wn + ni * 16 + l16;
            bf[ni] = *(const bf16x8*)&Bs[rf * 32 + (quad ^ ((rf >> 1) & 3)) * 8];
        }
#pragma unroll
        for (int mi = 0; mi < 4; mi++)
#pragma unroll
            for (int ni = 0; ni < 4; ni++)
                acc[mi][ni] = __builtin_amdgcn_mfma_f32_16x16x32_bf16(
                    af[mi], bf[ni], acc[mi][ni], 0, 0, 0);
    }

#pragma unroll
    for (int mi = 0; mi < 4; mi++)
#pragma unroll
        for (int ni = 0; ni < 4; ni++)
#pragma unroll
            for (int r = 0; r < 4; r++) {
                const int row = tm + wm + mi * 16 + quad * 4 + r;
                const int col = tn + wn + ni * 16 + l16;
                const int xr  = (vperm & (row >> 3) & 1) << 2;
                C[(size_t)row * N + (col ^ xr)] = (__bf16)(acc[mi][ni][r] * scale);
            }
}

// qkv block dispatch: qk branch tm-fastest (A-panel sharers same XCD);
// VT branch tn-fastest (xb-panel sharers same XCD; R9: FETCH 91->41MB).
__device__ __forceinline__ void qkv_block(int bx, const __bf16* xb,
                                          const __bf16* wqkt, const __bf16* wvt,
                                          __bf16* qk, __bf16* VT,
                                          __bf16* As, __bf16* Bs) {
    if (bx < 1024) {
        const int tm = (bx & 63) * 128, tn = (bx >> 6) * 128;
        const float scale = (tn < D_) ? QSCALE : 1.0f;
        gemm_body_bf16(xb, wqkt, qk, QKS, D_, tm, tn, scale, 0, As, Bs);
    } else {
        const int b2 = bx - 1024;
        const int tn = (b2 & 63) * 128, tm = (b2 >> 6) * 128;
        gemm_body_bf16(wvt, xb, VT, NTOK, D_, tm, tn, 1.0f, 1, As, Bs);
    }
}

// ---------------- gemm_o body: out = ctx Wo + bo (fp32 epilogue) ----------------
__device__ __forceinline__ void gemmo_body(int bid, const __bf16* __restrict__ A,
                                           const __bf16* __restrict__ Bt,
                                           float* __restrict__ C,
                                           const float* __restrict__ bias,
                                           __bf16* As, __bf16* Bs) {
    const int tid  = threadIdx.x;
    const int wave = tid >> 6, lane = tid & 63;
    const int quad = lane >> 4, l16 = lane & 15;
    const int tm = (bid & 63) * 128, tn = (bid >> 6) * 128;
    const int wm = (wave & 1) * 64, wn = (wave >> 1) * 64;
    const int N = D_, K = D_;
    f32x4 acc[4][4] = {};

    for (int k0 = 0; k0 < K; k0 += 32) {
        __syncthreads();
#pragma unroll
        for (int s = 0; s < 2; s++) {
            const int cb = s * 256 + wave * 64;
            const int c  = cb + lane;
            const int row = c >> 2;
            const int kc  = ((c & 3) ^ ((row >> 1) & 3)) * 8;
            __builtin_amdgcn_global_load_lds(GPTR(A + (size_t)(tm + row) * K + k0 + kc),
                                             LPTR(As + cb * 8), 16, 0, 0);
            __builtin_amdgcn_global_load_lds(GPTR(Bt + (size_t)(tn + row) * K + k0 + kc),
                                             LPTR(Bs + cb * 8), 16, 0, 0);
        }
        __syncthreads();

        bf16x8 af[4], bf[4];
#pragma unroll
        for (int mi = 0; mi < 4; mi++) {
            const int rf = wm + mi * 16 + l16;
            af[mi] = *(const bf16x8*)&As[rf * 32 + (quad ^ ((rf >> 1) & 3)) * 8];
        }
#pragma unroll
        for (int ni = 0; ni < 4; ni++) {
            const int rf = wn + ni * 16 + l16;
            bf[ni] = *(const bf16x8*)&Bs[rf * 32 + (quad ^ ((rf >> 1) & 3)) * 8];
        }
#pragma unroll
        for (int mi = 0; mi < 4; mi++)
#pragma unroll
            for (int ni = 0; ni < 4; ni++)
                acc[mi][ni] = __builtin_amdgcn_mfma_f32_16x16x32_bf16(
                    af[mi], bf[ni], acc[mi][ni], 0, 0, 0);
    }

#pragma unroll
    for (int mi = 0; mi < 4; mi++)
#pragma unroll
        for (int ni = 0; ni < 4; ni++)
#pragma unroll
            for (int r = 0; r < 4; r++) {
                const int row = tm + wm + mi * 16 + quad * 4 + r;
                const int col = tn + wn + ni * 16 + l16;
                C[(size_t)row * N + col] = acc[mi][ni][r] + bias[col];
            }
}

__device__ __forceinline__ short bf16_bits(float f) {
    __bf16 h = (__bf16)f;
    return __builtin_bit_cast(short, h);
}

// ---------------- causal flash attention body (R14/R16 structure) ----------------
// 64-row chunk pairs, 4 blocks/CU all-resident, uniform 33 iters/block.
// hb = (bid>>7)*8 + (bid&7): same-(h,b) blocks share an XCD (FETCH 147->32MB).
// Conflict-free V path: vperm'd VT producer + (l16>>3) XOR half-select.
__device__ __forceinline__ void attn_body(int bid, const __bf16* __restrict__ Qb,
                                          const __bf16* __restrict__ Kb,
                                          const __bf16* __restrict__ VT,
                                          __bf16* __restrict__ ctx,
                                          __bf16 (*Ks)[64 * 64],
                                          __bf16 (*Vs)[64 * 64]) {
    const int tid = threadIdx.x;
    const int wave = tid >> 6, lane = tid & 63;
    const int quad = lane >> 4, l16 = lane & 15;
    const int hb  = ((bid >> 7) << 3) | (bid & 7);
    const int qp  = (bid >> 3) & 15;
    const int h = hb >> 2, b = hb & 3;
    const size_t tok0 = (size_t)b * S_;
    const size_t hoff = (size_t)h * HD_;

    auto stage = [&](int kv, int buf) {
#pragma unroll
        for (int s = 0; s < 2; s++) {
            const int cb = s * 256 + wave * 64;
            const int c  = cb + lane;
            const int row = c >> 3;
            const int gc  = (c & 7) ^ (row & 7);
            __builtin_amdgcn_global_load_lds(
                GPTR(Kb + (size_t)(tok0 + kv + row) * QKS + hoff + gc * 8),
                LPTR(&Ks[buf][cb * 8]), 16, 0, 0);
            __builtin_amdgcn_global_load_lds(
                GPTR(VT + (hoff + row) * (size_t)NTOK + tok0 + kv + gc * 8),
                LPTR(&Vs[buf][cb * 8]), 16, 0, 0);
        }
    };

#pragma unroll 1
    for (int pass = 0; pass < 2; pass++) {
        const int j  = pass == 0 ? 31 - qp : qp;
        const int qb = j * 64;
        const int q0 = qb + wave * 16;

        bf16x8 qf[2];
#pragma unroll
        for (int ks = 0; ks < 2; ks++)
            qf[ks] = *(const bf16x8*)&Qb[(tok0 + q0 + l16) * QKS +
                                         hoff + ks * 32 + quad * 8];

        f32x4 oacc[4] = {};
        float lsum = 0.f;
        const int ktb = j;

        stage(0, 0);
        __syncthreads();

        for (int kt = 0; kt <= ktb; kt++) {
            const int cur = kt & 1;
            const int kv0 = kt * 64;
            if (kt < ktb) stage(kv0 + 64, 1 - cur);

            if (kv0 <= q0 + 15) {
                f32x4 st[4] = {};
#pragma unroll
                for (int ks = 0; ks < 2; ks++)
#pragma unroll
                    for (int ksub = 0; ksub < 4; ksub++) {
                        const int r = ksub * 16 + l16;
                        bf16x8 kf = *(const bf16x8*)
                            &Ks[cur][(r * 8 + (((ks * 4 + quad) ^ (r & 7)))) * 8];
                        st[ksub] = __builtin_amdgcn_mfma_f32_16x16x32_bf16(
                            kf, qf[ks], st[ksub], 0, 0, 0);
                    }
                if (kv0 + 63 > q0) {
#pragma unroll
                    for (int ksub = 0; ksub < 4; ksub++)
#pragma unroll
                        for (int r = 0; r < 4; r++) {
                            const int kg = kv0 + ksub * 16 + quad * 4 + r;
                            const int qg = q0 + l16;
                            if (kg > qg) st[ksub][r] = -1e30f;
                        }
                }
                short4v pfrag[4];
#pragma unroll
                for (int ksub = 0; ksub < 4; ksub++) {
                    float p0 = __builtin_amdgcn_exp2f(st[ksub][0]);
                    float p1 = __builtin_amdgcn_exp2f(st[ksub][1]);
                    float p2 = __builtin_amdgcn_exp2f(st[ksub][2]);
                    float p3 = __builtin_amdgcn_exp2f(st[ksub][3]);
                    lsum += (p0 + p1) + (p2 + p3);
                    short4v pf = {bf16_bits(p0), bf16_bits(p1),
                                  bf16_bits(p2), bf16_bits(p3)};
                    pfrag[ksub] = pf;
                }
#pragma unroll
                for (int ksub = 0; ksub < 4; ksub++)
#pragma unroll
                    for (int hs = 0; hs < 4; hs++) {
                        const int row = hs * 16 + l16;
                        const int swz = (ksub * 2 + (quad >> 1)) ^ (row & 7);
                        short4v vf = *(const short4v*)
                            &Vs[cur][row * 64 + swz * 8 + ((quad ^ (l16 >> 3)) & 1) * 4];
                        oacc[hs] = __builtin_amdgcn_mfma_f32_16x16x16bf16_1k(
                            vf, pfrag[ksub], oacc[hs], 0, 0, 0);
                    }
            }
            __syncthreads();
        }

        {
            float v = lsum;
            v += __shfl_xor(v, 16);
            v += __shfl_xor(v, 32);
            const float rl = 1.0f / v;
#pragma unroll
            for (int hs = 0; hs < 4; hs++) {
                bf16x4 o;
#pragma unroll
                for (int r = 0; r < 4; r++) o[r] = (__bf16)(oacc[hs][r] * rl);
                *(bf16x4*)&ctx[(tok0 + q0 + l16) * D_ + hoff +
                               hs * 16 + quad * 4] = o;
            }
        }
    }
}

// ================= fused cooperative kernels (R17) =================
// Theory: ~55us of the 235us total is inter-dispatch overhead (sum of kernel
// durs ~180us). Fuse 4 launches -> 2 with grid.sync between phases; kernel
// bodies unchanged. launch_bounds guarantee the coop residency targets.

__global__ __launch_bounds__(256, 6) void k_prep_qkv(const float* __restrict__ x,
                                                     __bf16* __restrict__ xb,
                                                     const float* __restrict__ Wq,
                                                     const float* __restrict__ Wk,
                                                     const float* __restrict__ Wv,
                                                     const float* __restrict__ Wo,
                                                     __bf16* __restrict__ wqkt,
                                                     __bf16* __restrict__ wvt,
                                                     __bf16* __restrict__ wot,
                                                     __bf16* __restrict__ qk,
                                                     __bf16* __restrict__ VT) {
    __shared__ __bf16 As[128 * 32];
    __shared__ __bf16 Bs[128 * 32];
    const int bid = blockIdx.x;
    for (int u = bid; u < 8192; u += 1536)
        prep_unit(u, x, xb, Wq, Wk, Wv, Wo, wqkt, wvt, wot, (float*)As);
    __threadfence();            // cross-XCD visibility of xb/wqkt/wvt
    cg::this_grid().sync();
    qkv_block(bid, xb, wqkt, wvt, qk, VT, As, Bs);
}

__global__ __launch_bounds__(256, 4) void k_attn_o(const __bf16* __restrict__ Qb,
                                                   const __bf16* __restrict__ Kb,
                                                   const __bf16* __restrict__ VT,
                                                   __bf16* __restrict__ ctx,
                                                   const __bf16* __restrict__ wot,
                                                   float* __restrict__ out,
                                                   const float* __restrict__ bias) {
    __shared__ __bf16 Ks[2][64 * 64];
    __shared__ __bf16 Vs[2][64 * 64];
    const int bid = blockIdx.x;
    attn_body(bid, Qb, Kb, VT, ctx, Ks, Vs);
    __threadfence();            // cross-XCD visibility of ctx
    cg::this_grid().sync();
    if (bid < 512)
        gemmo_body(bid, ctx, wot, out, bias, (__bf16*)Ks, (__bf16*)Vs);
}

// ================= fallback (R16) separate kernels =================
__global__ __launch_bounds__(256) void k_prep(const float* __restrict__ x,
                                              __bf16* __restrict__ xb,
                                              const float* __restrict__ Wq,
                                              const float* __restrict__ Wk,
                                              const float* __restrict__ Wv,
                                              const float* __restrict__ Wo,
                                              __bf16* __restrict__ wqkt,
                                              __bf16* __restrict__ wvt,
                                              __bf16* __restrict__ wot) {
    __shared__ float t[32][33];
    prep_unit(blockIdx.x, x, xb, Wq, Wk, Wv, Wo, wqkt, wvt, wot, (float*)t);
}

__global__ __launch_bounds__(256) void k_gemm_qkv(const __bf16* __restrict__ xb,
                                                  const __bf16* __restrict__ wqkt,
                                                  const __bf16* __restrict__ wvt,
                                                  __bf16* __restrict__ qk,
                                                  __bf16* __restrict__ VT) {
    __shared__ __bf16 As[128 * 32];
    __shared__ __bf16 Bs[128 * 32];
    qkv_block(blockIdx.x, xb, wqkt, wvt, qk, VT, As, Bs);
}

__global__ __launch_bounds__(256, 4) void k_attn(const __bf16* __restrict__ Qb,
                                                 const __bf16* __restrict__ Kb,
                                                 const __bf16* __restrict__ VT,
                                                 __bf16* __restrict__ ctx) {
    __shared__ __bf16 Ks[2][64 * 64];
    __shared__ __bf16 Vs[2][64 * 64];
    attn_body(blockIdx.x, Qb, Kb, VT, ctx, Ks, Vs);
}

__global__ __launch_bounds__(256) void k_gemm_o(const __bf16* __restrict__ A,
                                                const __bf16* __restrict__ Bt,
                                                float* __restrict__ C,
                                                const float* __restrict__ bias) {
    __shared__ __bf16 As[128 * 32];
    __shared__ __bf16 Bs[128 * 32];
    gemmo_body(blockIdx.x + blockIdx.y * 64, A, Bt, C, bias, As, Bs);
}

// ---------------- launch ----------------
extern "C" void kernel_launch(void* const* d_in, const int* in_sizes, int n_in,
                              void* d_out, int out_size, void* d_ws, size_t ws_size,
                              hipStream_t stream) {
    const float* x  = (const float*)d_in[0];
    const float* Wq = (const float*)d_in[1];
    const float* Wk = (const float*)d_in[2];
    const float* Wv = (const float*)d_in[3];
    const float* Wo = (const float*)d_in[4];
    const float* bo = (const float*)d_in[5];
    float* out = (float*)d_out;

    char* p = (char*)d_ws;
    __bf16* xb   = (__bf16*)p; p += (size_t)NTOK * D_ * 2;   // 16 MB
    __bf16* wqkt = (__bf16*)p; p += (size_t)2 * D_ * D_ * 2; // 4 MB
    __bf16* wvt  = (__bf16*)p; p += (size_t)D_ * D_ * 2;     // 2 MB
    __bf16* wot  = (__bf16*)p; p += (size_t)D_ * D_ * 2;     // 2 MB
    __bf16* qk   = (__bf16*)p; p += (size_t)NTOK * QKS * 2;  // 32 MB [tok][Q|K]
    __bf16* VT   = (__bf16*)p; p += (size_t)NTOK * D_ * 2;   // 16 MB [d][tok]
    __bf16* ctx  = xb;            // xb dead after qkv phase
    __bf16* Kb   = qk + D_;

    // one-time residency check: coop launch requires all blocks co-resident.
    static int mode = -1;
    if (mode < 0) {
        int b1 = 0, b2 = 0;
        hipOccupancyMaxActiveBlocksPerMultiprocessor(&b1, k_prep_qkv, 256, 0);
        hipOccupancyMaxActiveBlocksPerMultiprocessor(&b2, k_attn_o, 256, 0);
        mode = (b1 >= 6 && b2 >= 4) ? 1 : 0;
    }

    if (mode == 1) {
        void* a1[] = {(void*)&x, (void*)&xb, (void*)&Wq, (void*)&Wk, (void*)&Wv,
                      (void*)&Wo, (void*)&wqkt, (void*)&wvt, (void*)&wot,
                      (void*)&qk, (void*)&VT};
        hipLaunchCooperativeKernel((const void*)k_prep_qkv, dim3(1536), dim3(256),
                                   a1, 0, stream);
        void* a2[] = {(void*)&qk, (void*)&Kb, (void*)&VT, (void*)&ctx,
                      (void*)&wot, (void*)&out, (void*)&bo};
        hipLaunchCooperativeKernel((const void*)k_attn_o, dim3(1024), dim3(256),
                                   a2, 0, stream);
    } else {
        k_prep<<<dim3(8192), 256, 0, stream>>>(x, xb, Wq, Wk, Wv, Wo,
                                               wqkt, wvt, wot);
        k_gemm_qkv<<<dim3(1024 + 512), 256, 0, stream>>>(xb, wqkt, wvt, qk, VT);
        k_attn<<<dim3(1024), 256, 0, stream>>>(qk, Kb, VT, ctx);
        k_gemm_o<<<dim3(64, 8), 256, 0, stream>>>(ctx, wot, out, bo);
    }
}